// Round 6
// baseline (132.456 us; speedup 1.0000x reference)
//
#include <hip/hip_runtime.h>

typedef _Float16 half8 __attribute__((ext_vector_type(8)));
typedef float floatx4 __attribute__((ext_vector_type(4)));

#define IN_DIM 256
#define OUT_DIM 256
#define M_TILE 32

// Quantize weight -> f16 in MFMA-A-fragment-permuted order:
//   perm[((ct*8 + ks)*64 + lane)*8 + e] = rne(W[ct*16 + (lane&15)][ks*32 + (lane>>4)*8 + e] * 100)
// Each gemm A-frag load is one fully-coalesced 16B/lane dwordx4 from the
// L1/L2-hot 128KB buffer. Also quantizes bias and writes the scalar output.
__global__ void quant_kernel(const float* __restrict__ w,
                             const float* __restrict__ bias,
                             const float* __restrict__ in_scale,
                             _Float16* __restrict__ wqp,
                             float* __restrict__ bq,
                             float* __restrict__ out_scalar) {
    int t = blockIdx.x * blockDim.x + threadIdx.x;
    if (t < (OUT_DIM * IN_DIM) / 8) {
        int lane = t & 63;
        int ks   = (t >> 6) & 7;
        int ct   = t >> 9;
        int row  = ct * 16 + (lane & 15);
        int k0   = ks * 32 + (lane >> 4) * 8;
        const float* src = w + row * IN_DIM + k0;
        half8 h;
#pragma unroll
        for (int e = 0; e < 8; ++e)
            h[e] = (_Float16)rintf(src[e] * 100.0f); // jnp.round = round-half-even
        *((half8*)wqp + t) = h;
    }
    if (t < OUT_DIM) {
        float s2 = in_scale[0] * 100.0f;
        bq[t] = rintf(bias[t] * s2);
    }
    if (t == 0 && out_scalar != nullptr)
        out_scalar[0] = in_scale[0] * 100.0f;
}

// async 16B global->LDS DMA: dest = wave-uniform LDS base + lane*16 (m104/m108)
__device__ __forceinline__ void gl_lds16(const int* g, int* lds_row_base) {
    __builtin_amdgcn_global_load_lds(
        (const __attribute__((address_space(1))) void*)g,
        (__attribute__((address_space(3))) void*)lds_row_base,
        16, 0, 0);
}

// 32-row x 256-col tile per block. c_x staged as raw int32 via global_load_lds
// (zero VGPR round-trip, 8 DMAs/wave in flight). Source chunks XOR-permuted so
// LDS chunk c of row r holds global chunk c^(r&7) -> frag ds_read_b128s are
// bank-balanced (8 lanes per 4-bank group = minimum). int->f16 cvt in K-loop.
__global__ __launch_bounds__(256, 4) void gemm_kernel(const int* __restrict__ cx,
                                                      const _Float16* __restrict__ wqp,
                                                      const float* __restrict__ bq,
                                                      float* __restrict__ out) {
    __shared__ int ctile[M_TILE * IN_DIM];   // 32 KB, no padding (DMA constraint)

    const int t    = threadIdx.x;
    const int wave = t >> 6;
    const int lane = t & 63;
    const int m16  = lane & 15;
    const int quad = lane >> 4;

    const size_t m0 = (size_t)blockIdx.x * M_TILE;

    // ---- async stage: wave stages rows wave*8 .. wave*8+7 (1KB DMA each) ----
    {
        const int* gbase = cx + (m0 + wave * 8) * IN_DIM;
#pragma unroll
        for (int i = 0; i < 8; ++i) {
            // lane loads global chunk (lane ^ i) of row r (r&7 == i)
            const int* g = gbase + i * IN_DIM + ((lane ^ i) << 2);
            gl_lds16(g, &ctile[(wave * 8 + i) * IN_DIM]);
        }
    }

    // ---- prefetch ks=0 A-frags while the DMA drains ----
    const half8* wbase = (const half8*)wqp;
    half8 acur[4], anext[4];
#pragma unroll
    for (int i = 0; i < 4; ++i)
        acur[i] = wbase[((wave * 4 + i) * 8 + 0) * 64 + lane];

    __syncthreads();   // vmcnt(0) drain: DMA complete

    floatx4 acc[4][2] = {};
    const int s = m16 & 7;                 // row-chunk swizzle key (j*16 == 0 mod 8)

#pragma unroll
    for (int ks = 0; ks < 8; ++ks) {
        if (ks < 7) {
#pragma unroll
            for (int i = 0; i < 4; ++i)    // software prefetch next A-frags (L1/L2)
                anext[i] = wbase[((wave * 4 + i) * 8 + (ks + 1)) * 64 + lane];
        }

        // B-frags: lane needs ints [ks*32+quad*8, +8) of rows j*16+m16.
        // Global chunk c0 = ks*8+quad*2 lives at LDS chunk c0^s; c0+1 at (c0^s)^1.
        const int pos0 = ((ks * 8 + quad * 2) ^ s) << 2;   // int offset
        const int pos1 = pos0 ^ 4;
        half8 bfr[2];
#pragma unroll
        for (int j = 0; j < 2; ++j) {
            const int rb = (j * 16 + m16) * IN_DIM;
            int4 lo = *(const int4*)&ctile[rb + pos0];     // ds_read_b128, balanced
            int4 hi = *(const int4*)&ctile[rb + pos1];
            half8 b;
            b[0] = (_Float16)lo.x; b[1] = (_Float16)lo.y;
            b[2] = (_Float16)lo.z; b[3] = (_Float16)lo.w;
            b[4] = (_Float16)hi.x; b[5] = (_Float16)hi.y;
            b[6] = (_Float16)hi.z; b[7] = (_Float16)hi.w;
            bfr[j] = b;
        }

#pragma unroll
        for (int i = 0; i < 4; ++i)
#pragma unroll
            for (int j = 0; j < 2; ++j)
                acc[i][j] = __builtin_amdgcn_mfma_f32_16x16x32_f16(acur[i], bfr[j], acc[i][j], 0, 0, 0);

#pragma unroll
        for (int i = 0; i < 4; ++i) acur[i] = anext[i];
    }

    // ---- epilogue: lane stores 4 consecutive out cols per tile as float4 ----
#pragma unroll
    for (int i = 0; i < 4; ++i) {
        int col = wave * 64 + i * 16 + quad * 4;
        floatx4 bv = *(const floatx4*)(bq + col);
#pragma unroll
        for (int j = 0; j < 2; ++j) {
            size_t row = m0 + j * 16 + m16;
            *(floatx4*)(out + row * OUT_DIM + col) = acc[i][j] + bv;
        }
    }
}

extern "C" void kernel_launch(void* const* d_in, const int* in_sizes, int n_in,
                              void* d_out, int out_size, void* d_ws, size_t ws_size,
                              hipStream_t stream) {
    const int*   cx       = (const int*)d_in[0];
    const float* w        = (const float*)d_in[1];
    const float* bias     = (const float*)d_in[2];
    const float* in_scale = (const float*)d_in[3];
    float* out = (float*)d_out;

    _Float16* wqp = (_Float16*)d_ws;                              // 128 KB, permuted
    float*    bq  = (float*)((char*)d_ws + OUT_DIM * IN_DIM * 2); // 1 KB

    const int rows = in_sizes[0] / IN_DIM;          // 65536
    const size_t gemm_elems = (size_t)rows * OUT_DIM;
    float* out_scalar = ((size_t)out_size > gemm_elems) ? (out + gemm_elems) : nullptr;

    quant_kernel<<<32, 256, 0, stream>>>(w, bias, in_scale, wqp, bq, out_scalar);
    gemm_kernel<<<rows / M_TILE, 256, 0, stream>>>(cx, wqp, bq, out);
}